// Round 4
// baseline (689.329 us; speedup 1.0000x reference)
//
#include <hip/hip_runtime.h>
#include <cstdint>

#define I_NODES 32767
#define N_NODES 65535
#define NLEAF   32768

typedef float f32x4 __attribute__((ext_vector_type(4)));
typedef short bf16x8 __attribute__((ext_vector_type(8)));
typedef int   i32x4 __attribute__((ext_vector_type(4)));

__device__ __forceinline__ float sigmoidf_(float v) {
    return 1.0f / (1.0f + __expf(-v));
}
__device__ __forceinline__ float tanhf_(float v) {
    return 1.0f - 2.0f / (1.0f + __expf(2.0f * v));
}
__device__ __forceinline__ short f2bf(float f) {
    union { float f; unsigned u; } v; v.f = f;
    unsigned r = (v.u + 0x7FFF + ((v.u >> 16) & 1)) >> 16;
    return (short)r;
}
__device__ __forceinline__ float bf2f(short b) {
    union { float f; unsigned u; } v; v.u = ((unsigned)(unsigned short)b) << 16;
    return v.f;
}

// ---------------------------------------------------------------------------
// prep_all: weight transpose->bf16 + packed encoder weights + biases +
// feature pack + leaf-output constant + barrier-counter init. One launch.
// ---------------------------------------------------------------------------
__global__ __launch_bounds__(256) void prep_all(
    const float* __restrict__ w_xou, const float* __restrict__ w_btoa,
    const float* __restrict__ w_ca,  const float* __restrict__ w_cb,
    const float* __restrict__ w_ab,  const float* __restrict__ w_o1,
    const float* __restrict__ w_op1, const float* __restrict__ w_tb1,
    const float* __restrict__ w_ft1, const float* __restrict__ w_jn1,
    const float* __restrict__ w_op2, const float* __restrict__ w_tb2,
    const float* __restrict__ w_ft2, const float* __restrict__ w_jn2,
    const float* __restrict__ b_op1, const float* __restrict__ b_tb1,
    const float* __restrict__ b_ft1, const float* __restrict__ b_jn1,
    const float* __restrict__ b_op2, const float* __restrict__ b_tb2,
    const float* __restrict__ b_ft2, const float* __restrict__ b_jn2,
    const float* __restrict__ oper,  const float* __restrict__ tbf,
    const float* __restrict__ ftf,   const float* __restrict__ jnf,
    const float* __restrict__ b_o1,  const float* __restrict__ w_o2,
    const float* __restrict__ b_o2,
    short* __restrict__ wT_xou, short* __restrict__ wT_btoa,
    short* __restrict__ wT_ca,  short* __restrict__ wT_cb,
    short* __restrict__ wT_ab,  short* __restrict__ wT_o1,
    short* __restrict__ W1T,    short* __restrict__ W2T,
    float* __restrict__ b1cat,  float* __restrict__ b2cat,
    short* __restrict__ xfeat,  float* __restrict__ outv,
    int* __restrict__ bar)
{
    int r = blockIdx.x * 256 + threadIdx.x;
    if (r < 196608) { wT_xou[r] = f2bf(w_xou[(size_t)(r % 256) * 768 + r / 256]); return; }
    r -= 196608;
    if (r < 81920)  { wT_btoa[r] = f2bf(w_btoa[(size_t)(r % 320) * 256 + r / 320]); return; }
    r -= 81920;
    if (r < 65536)  { wT_ca[r] = f2bf(w_ca[(size_t)(r % 256) * 256 + r / 256]); return; }
    r -= 65536;
    if (r < 65536)  { wT_cb[r] = f2bf(w_cb[(size_t)(r % 256) * 256 + r / 256]); return; }
    r -= 65536;
    if (r < 65536)  { wT_ab[r] = f2bf(w_ab[(size_t)(r % 256) * 256 + r / 256]); return; }
    r -= 65536;
    if (r < 32768)  { wT_o1[r] = f2bf(w_o1[(size_t)(r % 256) * 128 + r / 256]); return; }
    r -= 32768;
    if (r < 24576) {
        int j = r / 96, k = r % 96;
        int s = j >> 6, jj = j & 63;
        int off = (s == 0) ? 0 : (s == 1) ? 4 : (s == 2) ? 15 : 33;
        int Ks  = (s == 0) ? 4 : (s == 1) ? 11 : (s == 2) ? 18 : 37;
        const float* w = (s == 0) ? w_op1 : (s == 1) ? w_tb1 : (s == 2) ? w_ft1 : w_jn1;
        W1T[r] = (k >= off && k < off + Ks) ? f2bf(w[(k - off) * 64 + jj]) : (short)0;
        return;
    }
    r -= 24576;
    if (r < 65536) {
        int j = r >> 8, k = r & 255;
        int s = j >> 6, jj = j & 63;
        const float* w = (s == 0) ? w_op2 : (s == 1) ? w_tb2 : (s == 2) ? w_ft2 : w_jn2;
        W2T[r] = ((k >> 6) == s) ? f2bf(w[(k & 63) * 64 + jj]) : (short)0;
        return;
    }
    r -= 65536;
    if (r < 256) {
        int s = r >> 6, jj = r & 63;
        b1cat[r] = (s == 0) ? b_op1[jj] : (s == 1) ? b_tb1[jj] : (s == 2) ? b_ft1[jj] : b_jn1[jj];
        return;
    }
    r -= 256;
    if (r < 256) {
        int s = r >> 6, jj = r & 63;
        b2cat[r] = (s == 0) ? b_op2[jj] : (s == 1) ? b_tb2[jj] : (s == 2) ? b_ft2[jj] : b_jn2[jj];
        return;
    }
    r -= 256;
    if (r < 3145728) {
        int node = r / 96, f = r - node * 96;
        float v = 0.0f;
        if (node < I_NODES) {
            if (f < 4)       v = oper[node * 4 + f];
            else if (f < 15) v = tbf[node * 11 + (f - 4)];
            else if (f < 33) v = ftf[node * 18 + (f - 15)];
            else if (f < 70) v = jnf[node * 37 + (f - 33)];
        }
        xfeat[r] = f2bf(v);
        return;
    }
    r -= 3145728;
    if (r < 32768) {
        // leaf output: h=0 -> hid = relu(b_o1), out = sigmoid(b_o2 + hid.w_o2)
        float s = 0.0f;
        for (int k = 0; k < 128; k++) s += fmaxf(b_o1[k], 0.0f) * w_o2[k];
        outv[I_NODES + r] = sigmoidf_(s + b_o2[0]);
        return;
    }
    r -= 32768;
    if (r == 0) *bar = 0;
}

// ---------------------------------------------------------------------------
// MFMA GEMM core: C = act(A[32768 x K] @ B + bias), B transposed Bt[Nn x K] bf16.
// BM=BN=128, BK=32, 256 threads = 4 waves, acc 4x4 of 16x16x32.
// ASRC: 0 = A bf16, 1 = A fp32 (converted during LDS staging).
// MODE 0: fp32 out0 with ACT. MODE 1: xou split (Nn=768).
// MODE 2: bf16 bout with ACT. MODE 3: t = e1*caf + sigmoid(v)*e2 -> bout.
// MODE 4: head+out fusion (Nn=128): p = relu(v)·w_o2, row-reduce, sigmoid->outv.
// ---------------------------------------------------------------------------
template <int ACT, int MODE, int ASRC>
__device__ __forceinline__ void gemm_body(
    short* Asl, short* Bsl,
    const void* __restrict__ Araw, const short* __restrict__ Bt,
    const float* __restrict__ bias,
    float* __restrict__ fout0, const float* __restrict__ caf,
    float* __restrict__ fout1, float* __restrict__ fout2,
    short* __restrict__ bout,
    const short* __restrict__ e1, const short* __restrict__ e2,
    const float* __restrict__ w_o2, const float* __restrict__ b_o2,
    float* __restrict__ outv,
    int K, int Nn)
{
    const int tid = threadIdx.x;
    const int bm = blockIdx.x * 128;
    const int bn = blockIdx.y * 128;
    const int wave = tid >> 6, lane = tid & 63;
    const int m = lane & 15, q = lane >> 4;
    const int rw = (wave & 1) * 64, cw = (wave >> 1) * 64;

    f32x4 acc[4][4] = {};

    for (int k0 = 0; k0 < K; k0 += 32) {
#pragma unroll
        for (int i = 0; i < 2; i++) {
            int id = tid + i * 256;
            int row = id >> 2, ch = id & 3;
            if (ASRC == 0) {
                const short* As = (const short*)Araw;
                i32x4 va = *(const i32x4*)(As + (size_t)(bm + row) * K + k0 + ch * 8);
                *(i32x4*)&Asl[row * 40 + ch * 8] = va;
            } else {
                const float* Af = (const float*)Araw;
                const float* src = Af + (size_t)(bm + row) * K + k0 + ch * 8;
                f32x4 a0 = *(const f32x4*)src;
                f32x4 a1 = *(const f32x4*)(src + 4);
                bf16x8 t;
                t[0] = f2bf(a0[0]); t[1] = f2bf(a0[1]); t[2] = f2bf(a0[2]); t[3] = f2bf(a0[3]);
                t[4] = f2bf(a1[0]); t[5] = f2bf(a1[1]); t[6] = f2bf(a1[2]); t[7] = f2bf(a1[3]);
                *(bf16x8*)&Asl[row * 40 + ch * 8] = t;
            }
            i32x4 vb = *(const i32x4*)(Bt + (size_t)(bn + row) * K + k0 + ch * 8);
            *(i32x4*)&Bsl[row * 40 + ch * 8] = vb;
        }
        __syncthreads();

        bf16x8 bfrag[4];
#pragma unroll
        for (int ct = 0; ct < 4; ct++)
            bfrag[ct] = *(const bf16x8*)&Bsl[(cw + ct * 16 + m) * 40 + q * 8];
#pragma unroll
        for (int rt = 0; rt < 4; rt++) {
            bf16x8 afrag = *(const bf16x8*)&Asl[(rw + rt * 16 + m) * 40 + q * 8];
#pragma unroll
            for (int ct = 0; ct < 4; ct++)
                acc[rt][ct] = __builtin_amdgcn_mfma_f32_16x16x32_bf16(
                    afrag, bfrag[ct], acc[rt][ct], 0, 0, 0);
        }
        __syncthreads();
    }

    if (MODE == 4) {
        // fused output head: per-thread partial dot with w_o2 over its cols
        float part[4][4];
#pragma unroll
        for (int rt = 0; rt < 4; rt++)
#pragma unroll
            for (int r = 0; r < 4; r++) part[rt][r] = 0.0f;
#pragma unroll
        for (int ct = 0; ct < 4; ct++) {
            int col = cw + ct * 16 + m;
            float bv = bias[col];
            float wv = w_o2[col];
#pragma unroll
            for (int rt = 0; rt < 4; rt++)
#pragma unroll
                for (int r = 0; r < 4; r++)
                    part[rt][r] += fmaxf(acc[rt][ct][r] + bv, 0.0f) * wv;
        }
#pragma unroll
        for (int rt = 0; rt < 4; rt++)
#pragma unroll
            for (int r = 0; r < 4; r++) {
#pragma unroll
                for (int off = 1; off < 16; off <<= 1)
                    part[rt][r] += __shfl_xor(part[rt][r], off);
            }
        float* sred = (float*)Asl;   // 128 rows x 2 halves
        if (m == 0) {
#pragma unroll
            for (int rt = 0; rt < 4; rt++)
#pragma unroll
                for (int r = 0; r < 4; r++)
                    sred[(rw + rt * 16 + q * 4 + r) * 2 + (cw >> 6)] = part[rt][r];
        }
        __syncthreads();
        if (tid < 128) {
            int g = bm + tid;
            if (g < I_NODES)
                outv[g] = sigmoidf_(sred[tid * 2] + sred[tid * 2 + 1] + b_o2[0]);
        }
        return;
    }

#pragma unroll
    for (int rt = 0; rt < 4; rt++) {
#pragma unroll
        for (int ct = 0; ct < 4; ct++) {
            int col = bn + cw + ct * 16 + m;
            float bv = bias[col];
#pragma unroll
            for (int r = 0; r < 4; r++) {
                int row = bm + rw + rt * 16 + q * 4 + r;
                float v = acc[rt][ct][r] + bv;
                if (MODE == 0) {
                    if (ACT == 1) v = fmaxf(v, 0.0f);
                    else if (ACT == 2) v = sigmoidf_(v);
                    fout0[(size_t)row * Nn + col] = v;
                } else if (MODE == 1) {
                    int seg = col >> 8, cc = col & 255;
                    if (seg == 0)      fout0[(size_t)row * 256 + cc] = v;
                    else if (seg == 1) fout1[(size_t)row * 256 + cc] = sigmoidf_(v);
                    else               fout2[(size_t)row * 256 + cc] = sigmoidf_(v);
                } else if (MODE == 2) {
                    if (ACT == 1) v = fmaxf(v, 0.0f);
                    else if (ACT == 2) v = sigmoidf_(v);
                    bout[(size_t)row * Nn + col] = f2bf(v);
                } else {
                    size_t idx = (size_t)row * 256 + col;
                    float t = bf2f(e1[idx]) * caf[idx] + sigmoidf_(v) * bf2f(e2[idx]);
                    bout[idx] = f2bf(t);
                }
            }
        }
    }
}

template <int ACT, int MODE, int ASRC>
__global__ __launch_bounds__(256) void gemm_k(
    const void* A, const short* Bt, const float* bias,
    float* fout0, const float* caf, float* fout1, float* fout2,
    short* bout, const short* e1, const short* e2,
    const float* w_o2, const float* b_o2, float* outv,
    int K, int Nn)
{
    __shared__ short Asl[128 * 40];
    __shared__ short Bsl[128 * 40];
    gemm_body<ACT, MODE, ASRC>(Asl, Bsl, A, Bt, bias, fout0, caf, fout1, fout2,
                               bout, e1, e2, w_o2, b_o2, outv, K, Nn);
}

// two independent leaf GEMMs in one dispatch (blockIdx.z selects)
__global__ __launch_bounds__(256) void gemm_leafpair(
    const float* cbl, const short* wT_btoa, const float* b_btoa, short* cb,
    const float* cal, const short* wT_ca,   const float* b_ca,   short* wa)
{
    __shared__ short Asl[128 * 40];
    __shared__ short Bsl[128 * 40];
    if (blockIdx.z == 0)
        gemm_body<0, 2, 1>(Asl, Bsl, cbl, wT_btoa, b_btoa,
                           nullptr, nullptr, nullptr, nullptr, cb,
                           nullptr, nullptr, nullptr, nullptr, nullptr, 320, 256);
    else
        gemm_body<2, 2, 1>(Asl, Bsl, cal, wT_ca, b_ca,
                           nullptr, nullptr, nullptr, nullptr, wa,
                           nullptr, nullptr, nullptr, nullptr, nullptr, 256, 256);
}

// ---------------------------------------------------------------------------
// all 15 tree levels in one kernel; 256 blocks x 1024 threads (co-resident),
// device-scope monotonic-counter barrier between levels.
// ---------------------------------------------------------------------------
__device__ __forceinline__ void gbar(int* bar, int target)
{
    __syncthreads();
    if (threadIdx.x == 0) {
        __threadfence();
        __hip_atomic_fetch_add(bar, 1, __ATOMIC_RELEASE, __HIP_MEMORY_SCOPE_AGENT);
        while (__hip_atomic_load(bar, __ATOMIC_ACQUIRE, __HIP_MEMORY_SCOPE_AGENT) < target)
            __builtin_amdgcn_s_sleep(2);
    }
    __syncthreads();
}

__global__ __launch_bounds__(1024, 4) void levels_fused(
    float* __restrict__ c, const float* __restrict__ ff,
    const float* __restrict__ xx, const float* __restrict__ rr,
    const short* __restrict__ x, short* __restrict__ h, int* bar)
{
    for (int n = 1; n <= 15; n++) {
        int d = 15 - n;
        int start = (1 << d) - 1;
        int total = (1 << d) * 256;
        for (int idx = blockIdx.x * 1024 + threadIdx.x; idx < total; idx += 256 * 1024) {
            int p = start + (idx >> 8);
            int j = idx & 255;
            size_t pr = (size_t)p * 256 + j;
            float cs = c[(size_t)(2 * p + 1) * 256 + j] + c[(size_t)(2 * p + 2) * 256 + j];
            float f = ff[pr];
            float cv = f * cs + (1.0f - f) * xx[pr];
            c[pr] = cv;
            float r = rr[pr];
            h[pr] = f2bf(r * tanhf_(cv) + (1.0f - r) * bf2f(x[pr]));
        }
        if (n < 15) gbar(bar, 256 * n);
    }
}

// ---------------------------------------------------------------------------
extern "C" void kernel_launch(void* const* d_in, const int* in_sizes, int n_in,
                              void* d_out, int out_size, void* d_ws, size_t ws_size,
                              hipStream_t stream)
{
    const float* oper  = (const float*)d_in[0];
    const float* tbf   = (const float*)d_in[1];
    const float* ftf   = (const float*)d_in[2];
    const float* jnf   = (const float*)d_in[3];
    const float* c_a   = (const float*)d_in[4];
    const float* c_b   = (const float*)d_in[5];
    const float* w_op1 = (const float*)d_in[6],  *b_op1 = (const float*)d_in[7];
    const float* w_op2 = (const float*)d_in[8],  *b_op2 = (const float*)d_in[9];
    const float* w_tb1 = (const float*)d_in[10], *b_tb1 = (const float*)d_in[11];
    const float* w_tb2 = (const float*)d_in[12], *b_tb2 = (const float*)d_in[13];
    const float* w_ft1 = (const float*)d_in[14], *b_ft1 = (const float*)d_in[15];
    const float* w_ft2 = (const float*)d_in[16], *b_ft2 = (const float*)d_in[17];
    const float* w_jn1 = (const float*)d_in[18], *b_jn1 = (const float*)d_in[19];
    const float* w_jn2 = (const float*)d_in[20], *b_jn2 = (const float*)d_in[21];
    const float* w_xou = (const float*)d_in[22], *b_xou = (const float*)d_in[23];
    const float* w_ab  = (const float*)d_in[24], *b_ab  = (const float*)d_in[25];
    const float* w_btoa= (const float*)d_in[26], *b_btoa= (const float*)d_in[27];
    const float* w_ca  = (const float*)d_in[28], *b_ca  = (const float*)d_in[29];
    const float* w_cb  = (const float*)d_in[30], *b_cb  = (const float*)d_in[31];
    const float* w_o1  = (const float*)d_in[32], *b_o1  = (const float*)d_in[33];
    const float* w_o2  = (const float*)d_in[34], *b_o2  = (const float*)d_in[35];

    char* WS = (char*)d_ws;
    short* wT_xou  = (short*)WS;                 // 196608
    short* wT_btoa = wT_xou  + 196608;           // 81920
    short* wT_ca   = wT_btoa + 81920;            // 65536
    short* wT_cb   = wT_ca   + 65536;            // 65536
    short* wT_ab   = wT_cb   + 65536;            // 65536
    short* wT_o1   = wT_ab   + 65536;            // 32768
    short* W1T     = wT_o1   + 32768;            // 24576
    short* W2T     = W1T     + 24576;            // 65536
    float* b1cat   = (float*)(W2T + 65536);      // 256
    float* b2cat   = b1cat + 256;                // 256
    int*   bar     = (int*)(WS + 0x1F0000);      // barrier counter

    const size_t MB = 1 << 20;
    const size_t OFF_XF   = 2 * MB;
    const size_t OFF_HE   = OFF_XF   + (size_t)32768 * 96 * 2;
    const size_t OFF_X    = OFF_HE   + (size_t)32768 * 256 * 2;
    const size_t OFF_XX   = OFF_X    + (size_t)32768 * 256 * 2;
    const size_t OFF_FF   = OFF_XX   + (size_t)32768 * 256 * 4;
    const size_t OFF_RR   = OFF_FF   + (size_t)32768 * 256 * 4;
    const size_t OFF_C    = OFF_RR   + (size_t)32768 * 256 * 4;
    const size_t OFF_H    = OFF_C    + (size_t)65536 * 256 * 4;
    const size_t OFF_CB   = OFF_H    + (size_t)32768 * 256 * 2;
    const size_t OFF_WA   = OFF_CB   + (size_t)32768 * 256 * 2;

    short* xfeat = (short*)(WS + OFF_XF);
    short* henc  = (short*)(WS + OFF_HE);
    short* x     = (short*)(WS + OFF_X);
    float* xx    = (float*)(WS + OFF_XX);
    float* ff    = (float*)(WS + OFF_FF);
    float* rr    = (float*)(WS + OFF_RR);
    float* c     = (float*)(WS + OFF_C);
    short* h     = (short*)(WS + OFF_H);     // 32768 rows (internal + 1 pad)
    short* cb    = (short*)(WS + OFF_CB);
    short* wa    = (short*)(WS + OFF_WA);
    float* out   = (float*)d_out;
    const float* caf = c_a + (size_t)I_NODES * 256;
    const float* cbl = c_b + (size_t)I_NODES * 320;

    // 1. prep: weights + features + leaf outputs + barrier init (one launch)
    prep_all<<<14755, 256, 0, stream>>>(
        w_xou, w_btoa, w_ca, w_cb, w_ab, w_o1,
        w_op1, w_tb1, w_ft1, w_jn1, w_op2, w_tb2, w_ft2, w_jn2,
        b_op1, b_tb1, b_ft1, b_jn1, b_op2, b_tb2, b_ft2, b_jn2,
        oper, tbf, ftf, jnf, b_o1, w_o2, b_o2,
        wT_xou, wT_btoa, wT_ca, wT_cb, wT_ab, wT_o1, W1T, W2T, b1cat, b2cat,
        xfeat, out, bar);

    // 2. encoder: two MFMA GEMMs
    gemm_k<1, 2, 0><<<dim3(256, 2), 256, 0, stream>>>(
        xfeat, W1T, b1cat, nullptr, nullptr, nullptr, nullptr, henc,
        nullptr, nullptr, nullptr, nullptr, nullptr, 96, 256);
    gemm_k<1, 2, 0><<<dim3(256, 2), 256, 0, stream>>>(
        henc, W2T, b2cat, nullptr, nullptr, nullptr, nullptr, x,
        nullptr, nullptr, nullptr, nullptr, nullptr, 256, 256);

    // 3. xou: xx (raw f32), ff, rr (sigmoid f32)
    gemm_k<0, 1, 0><<<dim3(256, 6), 256, 0, stream>>>(
        x, wT_xou, b_xou, xx, nullptr, ff, rr, nullptr,
        nullptr, nullptr, nullptr, nullptr, nullptr, 256, 768);

    // 4. leaf chain: (cb | wa) -> t fused -> c_leaf
    gemm_leafpair<<<dim3(256, 2, 2), 256, 0, stream>>>(
        cbl, wT_btoa, b_btoa, cb, caf, wT_ca, b_ca, wa);
    gemm_k<0, 3, 0><<<dim3(256, 2), 256, 0, stream>>>(
        cb, wT_cb, b_cb, nullptr, caf, nullptr, nullptr, wa /*t in-place*/,
        wa, cb, nullptr, nullptr, nullptr, 256, 256);
    gemm_k<1, 0, 0><<<dim3(256, 2), 256, 0, stream>>>(
        wa, wT_ab, b_ab, c + (size_t)I_NODES * 256, nullptr, nullptr, nullptr,
        nullptr, nullptr, nullptr, nullptr, nullptr, nullptr, 256, 256);

    // 5. all 15 tree levels, one kernel with device barriers
    levels_fused<<<256, 1024, 0, stream>>>(c, ff, xx, rr, x, h, bar);

    // 6. output head fused with final dot+sigmoid (internal nodes)
    gemm_k<1, 4, 0><<<dim3(256, 1), 256, 0, stream>>>(
        h, wT_o1, b_o1, nullptr, nullptr, nullptr, nullptr, nullptr,
        nullptr, nullptr, w_o2, b_o2, out, 256, 128);
}

// Round 5
// 507.372 us; speedup vs baseline: 1.3586x; 1.3586x over previous
//
#include <hip/hip_runtime.h>
#include <cstdint>

#define I_NODES 32767
#define N_NODES 65535
#define NLEAF   32768
#define NT      32768          // node columns for channel-major activations
#define CSTRIDE 65536          // node columns for c_T

typedef float f32x4 __attribute__((ext_vector_type(4)));
typedef short bf16x8 __attribute__((ext_vector_type(8)));
typedef int   i32x4 __attribute__((ext_vector_type(4)));

__device__ __forceinline__ float sigmoidf_(float v) {
    return 1.0f / (1.0f + __expf(-v));
}
__device__ __forceinline__ float tanhf_(float v) {
    return 1.0f - 2.0f / (1.0f + __expf(2.0f * v));
}
__device__ __forceinline__ short f2bf(float f) {
    union { float f; unsigned u; } v; v.f = f;
    unsigned r = (v.u + 0x7FFF + ((v.u >> 16) & 1)) >> 16;
    return (short)r;
}
__device__ __forceinline__ float bf2f(short b) {
    union { float f; unsigned u; } v; v.u = ((unsigned)(unsigned short)b) << 16;
    return v.f;
}

// ---------------------------------------------------------------------------
// prep_all: weight transposes->bf16 (wT[outch][inch]) + packed encoder
// weights + biases + feature pack (node-major) + leaf-output constant.
// ---------------------------------------------------------------------------
__global__ __launch_bounds__(256) void prep_all(
    const float* __restrict__ w_xou, const float* __restrict__ w_btoa,
    const float* __restrict__ w_ca,  const float* __restrict__ w_cb,
    const float* __restrict__ w_ab,  const float* __restrict__ w_o1,
    const float* __restrict__ w_op1, const float* __restrict__ w_tb1,
    const float* __restrict__ w_ft1, const float* __restrict__ w_jn1,
    const float* __restrict__ w_op2, const float* __restrict__ w_tb2,
    const float* __restrict__ w_ft2, const float* __restrict__ w_jn2,
    const float* __restrict__ b_op1, const float* __restrict__ b_tb1,
    const float* __restrict__ b_ft1, const float* __restrict__ b_jn1,
    const float* __restrict__ b_op2, const float* __restrict__ b_tb2,
    const float* __restrict__ b_ft2, const float* __restrict__ b_jn2,
    const float* __restrict__ oper,  const float* __restrict__ tbf,
    const float* __restrict__ ftf,   const float* __restrict__ jnf,
    const float* __restrict__ b_o1,  const float* __restrict__ w_o2,
    const float* __restrict__ b_o2,
    short* __restrict__ wT_xou, short* __restrict__ wT_btoa,
    short* __restrict__ wT_ca,  short* __restrict__ wT_cb,
    short* __restrict__ wT_ab,  short* __restrict__ wT_o1,
    short* __restrict__ W1T,    short* __restrict__ W2T,
    float* __restrict__ b1cat,  float* __restrict__ b2cat,
    short* __restrict__ xfeat,  float* __restrict__ outv)
{
    int r = blockIdx.x * 256 + threadIdx.x;
    if (r < 196608) { wT_xou[r] = f2bf(w_xou[(size_t)(r % 256) * 768 + r / 256]); return; }
    r -= 196608;
    if (r < 81920)  { wT_btoa[r] = f2bf(w_btoa[(size_t)(r % 320) * 256 + r / 320]); return; }
    r -= 81920;
    if (r < 65536)  { wT_ca[r] = f2bf(w_ca[(size_t)(r % 256) * 256 + r / 256]); return; }
    r -= 65536;
    if (r < 65536)  { wT_cb[r] = f2bf(w_cb[(size_t)(r % 256) * 256 + r / 256]); return; }
    r -= 65536;
    if (r < 65536)  { wT_ab[r] = f2bf(w_ab[(size_t)(r % 256) * 256 + r / 256]); return; }
    r -= 65536;
    if (r < 32768)  { wT_o1[r] = f2bf(w_o1[(size_t)(r % 256) * 128 + r / 256]); return; }
    r -= 32768;
    if (r < 24576) {
        int j = r / 96, k = r % 96;
        int s = j >> 6, jj = j & 63;
        int off = (s == 0) ? 0 : (s == 1) ? 4 : (s == 2) ? 15 : 33;
        int Ks  = (s == 0) ? 4 : (s == 1) ? 11 : (s == 2) ? 18 : 37;
        const float* w = (s == 0) ? w_op1 : (s == 1) ? w_tb1 : (s == 2) ? w_ft1 : w_jn1;
        W1T[r] = (k >= off && k < off + Ks) ? f2bf(w[(k - off) * 64 + jj]) : (short)0;
        return;
    }
    r -= 24576;
    if (r < 65536) {
        int j = r >> 8, k = r & 255;
        int s = j >> 6, jj = j & 63;
        const float* w = (s == 0) ? w_op2 : (s == 1) ? w_tb2 : (s == 2) ? w_ft2 : w_jn2;
        W2T[r] = ((k >> 6) == s) ? f2bf(w[(k & 63) * 64 + jj]) : (short)0;
        return;
    }
    r -= 65536;
    if (r < 256) {
        int s = r >> 6, jj = r & 63;
        b1cat[r] = (s == 0) ? b_op1[jj] : (s == 1) ? b_tb1[jj] : (s == 2) ? b_ft1[jj] : b_jn1[jj];
        return;
    }
    r -= 256;
    if (r < 256) {
        int s = r >> 6, jj = r & 63;
        b2cat[r] = (s == 0) ? b_op2[jj] : (s == 1) ? b_tb2[jj] : (s == 2) ? b_ft2[jj] : b_jn2[jj];
        return;
    }
    r -= 256;
    if (r < 3145728) {
        int node = r / 96, f = r - node * 96;
        float v = 0.0f;
        if (node < I_NODES) {
            if (f < 4)       v = oper[node * 4 + f];
            else if (f < 15) v = tbf[node * 11 + (f - 4)];
            else if (f < 33) v = ftf[node * 18 + (f - 15)];
            else if (f < 70) v = jnf[node * 37 + (f - 33)];
        }
        xfeat[r] = f2bf(v);
        return;
    }
    r -= 3145728;
    if (r < 32768) {
        // leaf output: h=0 -> hid = relu(b_o1), out = sigmoid(b_o2 + hid.w_o2)
        float s = 0.0f;
        for (int k = 0; k < 128; k++) s += fmaxf(b_o1[k], 0.0f) * w_o2[k];
        outv[I_NODES + r] = sigmoidf_(s + b_o2[0]);
    }
}

// LDS-tiled transpose: c_a leaf slice [32768 x 256] f32 -> cafT [256 x 32768] f32
__global__ __launch_bounds__(256) void transpose_caf(
    const float* __restrict__ caf, float* __restrict__ cafT)
{
    __shared__ float tile[64][65];
    const int t = threadIdx.x;
    const int r0 = blockIdx.x * 64;   // leaf rows
    const int c0 = blockIdx.y * 64;   // channels
    const int lane = t & 63, seg = t >> 6;
#pragma unroll
    for (int i = 0; i < 16; i++) {
        int rr = seg + i * 4;
        tile[rr][lane] = caf[(size_t)(r0 + rr) * 256 + c0 + lane];
    }
    __syncthreads();
#pragma unroll
    for (int i = 0; i < 16; i++) {
        int cc = seg + i * 4;
        cafT[(size_t)(c0 + cc) * NT + r0 + lane] = tile[lane][cc];
    }
}

// ---------------------------------------------------------------------------
// Transposed-world MFMA GEMM: out_T[ch][node] = act( A_w[M x K] @ B + bias ).
// A_w = transposed weight, bf16 row-major [M][K]. Grid (M/128, 256).
// BLAYOUT 0: B node-major [32768 x K] (BSRC 0 bf16 / 1 fp32-convert).
// BLAYOUT 1: B channel-major bf16 [K x BN] (BSRC must be 0).
// MODE 0: fp32 fout[row*ON + COLOFF + col] with ACT.
// MODE 1: xou split by global row: 0-255 raw->xxT, 256-511 sig->ffT, 512-767 sig->rrT.
// MODE 2: bf16 bout[row*ON + col] with ACT.
// MODE 3: t-fusion: bout = e1*caf + sigmoid(v)*e2 (all channel-major, caf fp32).
// MODE 4: head fusion (M=128): out[col] = sigmoid(b_o2 + sum_row relu(v)*w_o2[row]).
// ---------------------------------------------------------------------------
template <int ACT, int MODE, int BSRC, int BLAYOUT>
__device__ __forceinline__ void gemm_body(
    short* Asl, short* Bsl,
    const short* __restrict__ A, const void* __restrict__ Braw,
    const float* __restrict__ bias,
    float* __restrict__ fout, float* __restrict__ fout1, float* __restrict__ fout2,
    short* __restrict__ bout,
    const float* __restrict__ caf, const short* __restrict__ e1,
    const short* __restrict__ e2,
    const float* __restrict__ w_o2, const float* __restrict__ b_o2,
    float* __restrict__ outv,
    int K, int BN, int ON, int COLOFF)
{
    const int tid = threadIdx.x;
    const int bm = blockIdx.x * 128;
    const int bn = blockIdx.y * 128;
    const int wave = tid >> 6, lane = tid & 63;
    const int m = lane & 15, q = lane >> 4;
    const int rw = (wave & 1) * 64, cw = (wave >> 1) * 64;

    f32x4 acc[4][4] = {};

    for (int k0 = 0; k0 < K; k0 += 32) {
        // A staging: [128 rows][32 k] from bf16 row-major
#pragma unroll
        for (int i = 0; i < 2; i++) {
            int id = tid + i * 256;
            int row = id >> 2, ch = id & 3;
            i32x4 va = *(const i32x4*)(A + (size_t)(bm + row) * K + k0 + ch * 8);
            *(i32x4*)&Asl[row * 40 + ch * 8] = va;
        }
        // B staging -> Bsl[n][k] (pitch 40)
        if (BLAYOUT == 0) {
#pragma unroll
            for (int i = 0; i < 2; i++) {
                int id = tid + i * 256;
                int row = id >> 2, ch = id & 3;
                if (BSRC == 0) {
                    const short* Bs = (const short*)Braw;
                    i32x4 vb = *(const i32x4*)(Bs + (size_t)(bn + row) * K + k0 + ch * 8);
                    *(i32x4*)&Bsl[row * 40 + ch * 8] = vb;
                } else {
                    const float* Bf = (const float*)Braw;
                    const float* src = Bf + (size_t)(bn + row) * K + k0 + ch * 8;
                    f32x4 a0 = *(const f32x4*)src;
                    f32x4 a1 = *(const f32x4*)(src + 4);
                    bf16x8 tv;
                    tv[0] = f2bf(a0[0]); tv[1] = f2bf(a0[1]); tv[2] = f2bf(a0[2]); tv[3] = f2bf(a0[3]);
                    tv[4] = f2bf(a1[0]); tv[5] = f2bf(a1[1]); tv[6] = f2bf(a1[2]); tv[7] = f2bf(a1[3]);
                    *(bf16x8*)&Bsl[row * 40 + ch * 8] = tv;
                }
            }
        } else {
            const short* Bs = (const short*)Braw;
            int nl = tid & 127, kh = tid >> 7;   // 128 n x 2 k-halves
            short vals[16];
#pragma unroll
            for (int kk = 0; kk < 16; kk++)
                vals[kk] = Bs[(size_t)(k0 + kh * 16 + kk) * BN + bn + nl];
            *(bf16x8*)&Bsl[nl * 40 + kh * 16]     = *(bf16x8*)&vals[0];
            *(bf16x8*)&Bsl[nl * 40 + kh * 16 + 8] = *(bf16x8*)&vals[8];
        }
        __syncthreads();

        bf16x8 bfrag[4];
#pragma unroll
        for (int ct = 0; ct < 4; ct++)
            bfrag[ct] = *(const bf16x8*)&Bsl[(cw + ct * 16 + m) * 40 + q * 8];
#pragma unroll
        for (int rt = 0; rt < 4; rt++) {
            bf16x8 afrag = *(const bf16x8*)&Asl[(rw + rt * 16 + m) * 40 + q * 8];
#pragma unroll
            for (int ct = 0; ct < 4; ct++)
                acc[rt][ct] = __builtin_amdgcn_mfma_f32_16x16x32_bf16(
                    afrag, bfrag[ct], acc[rt][ct], 0, 0, 0);
        }
        __syncthreads();
    }

    if (MODE == 4) {
        float part[4] = {};
#pragma unroll
        for (int ct = 0; ct < 4; ct++) {
#pragma unroll
            for (int rt = 0; rt < 4; rt++) {
#pragma unroll
                for (int r = 0; r < 4; r++) {
                    int row = rw + rt * 16 + q * 4 + r;
                    part[ct] += fmaxf(acc[rt][ct][r] + bias[row], 0.0f) * w_o2[row];
                }
            }
        }
#pragma unroll
        for (int ct = 0; ct < 4; ct++) {
            part[ct] += __shfl_xor(part[ct], 16);
            part[ct] += __shfl_xor(part[ct], 32);
        }
        float* sred = (float*)Asl;   // [2][128]
        if (q == 0) {
#pragma unroll
            for (int ct = 0; ct < 4; ct++)
                sred[(wave & 1) * 128 + cw + ct * 16 + m] = part[ct];
        }
        __syncthreads();
        if (tid < 128) {
            int g = bn + tid;
            if (g < I_NODES)
                outv[g] = sigmoidf_(sred[tid] + sred[128 + tid] + b_o2[0]);
        }
        return;
    }

#pragma unroll
    for (int rt = 0; rt < 4; rt++) {
#pragma unroll
        for (int ct = 0; ct < 4; ct++) {
            int col = bn + cw + ct * 16 + m;
#pragma unroll
            for (int r = 0; r < 4; r++) {
                int row = bm + rw + rt * 16 + q * 4 + r;
                float v = acc[rt][ct][r] + bias[row];
                if (MODE == 0) {
                    if (ACT == 1) v = fmaxf(v, 0.0f);
                    else if (ACT == 2) v = sigmoidf_(v);
                    fout[(size_t)row * ON + COLOFF + col] = v;
                } else if (MODE == 1) {
                    int seg = row >> 8, rl = row & 255;
                    if (seg == 0)      fout[(size_t)rl * NT + col] = v;
                    else if (seg == 1) fout1[(size_t)rl * NT + col] = sigmoidf_(v);
                    else               fout2[(size_t)rl * NT + col] = sigmoidf_(v);
                } else if (MODE == 2) {
                    if (ACT == 1) v = fmaxf(v, 0.0f);
                    else if (ACT == 2) v = sigmoidf_(v);
                    bout[(size_t)row * ON + col] = f2bf(v);
                } else {
                    size_t idx = (size_t)row * NT + col;
                    float t = bf2f(e1[idx]) * caf[idx] + sigmoidf_(v) * bf2f(e2[idx]);
                    bout[idx] = f2bf(t);
                }
            }
        }
    }
}

template <int ACT, int MODE, int BSRC, int BLAYOUT>
__global__ __launch_bounds__(256) void gemm_t(
    const short* A, const void* B, const float* bias,
    float* fout, float* fout1, float* fout2, short* bout,
    const float* caf, const short* e1, const short* e2,
    const float* w_o2, const float* b_o2, float* outv,
    int K, int BN, int ON, int COLOFF)
{
    __shared__ short Asl[128 * 40];
    __shared__ short Bsl[128 * 40];
    gemm_body<ACT, MODE, BSRC, BLAYOUT>(Asl, Bsl, A, B, bias, fout, fout1, fout2,
                                        bout, caf, e1, e2, w_o2, b_o2, outv,
                                        K, BN, ON, COLOFF);
}

// two independent leaf GEMMs in one dispatch (blockIdx.z selects)
__global__ __launch_bounds__(256) void gemm_leafpair(
    const short* wT_btoa, const float* cbl, const float* b_btoa, short* cbT,
    const short* wT_ca,   const float* cal, const float* b_ca,   short* waT)
{
    __shared__ short Asl[128 * 40];
    __shared__ short Bsl[128 * 40];
    if (blockIdx.z == 0)
        gemm_body<0, 2, 1, 0>(Asl, Bsl, wT_btoa, cbl, b_btoa,
                              nullptr, nullptr, nullptr, cbT,
                              nullptr, nullptr, nullptr, nullptr, nullptr, nullptr,
                              320, 0, NT, 0);
    else
        gemm_body<2, 2, 1, 0>(Asl, Bsl, wT_ca, cal, b_ca,
                              nullptr, nullptr, nullptr, waT,
                              nullptr, nullptr, nullptr, nullptr, nullptr, nullptr,
                              256, 0, NT, 0);
}

// ---------------------------------------------------------------------------
// all 15 tree levels; one block per channel (256 blocks x 1024 threads);
// only block-local __syncthreads needed (channels independent).
// ---------------------------------------------------------------------------
__global__ __launch_bounds__(1024) void levels_T(
    float* __restrict__ cT, const float* __restrict__ ffT,
    const float* __restrict__ xxT, const float* __restrict__ rrT,
    const short* __restrict__ xT, short* __restrict__ hT)
{
    const int j = blockIdx.x;
    float* crow = cT + (size_t)j * CSTRIDE;
    const float* frow = ffT + (size_t)j * NT;
    const float* xrow = xxT + (size_t)j * NT;
    const float* rrow = rrT + (size_t)j * NT;
    const short* xbrow = xT + (size_t)j * NT;
    short* hrow = hT + (size_t)j * NT;

    for (int n = 1; n <= 15; n++) {
        int d = 15 - n;
        int start = (1 << d) - 1;
        int cnt = 1 << d;
        for (int idx = threadIdx.x; idx < cnt; idx += 1024) {
            int p = start + idx;
            float cs = crow[2 * p + 1] + crow[2 * p + 2];
            float f = frow[p];
            float cv = f * cs + (1.0f - f) * xrow[p];
            crow[p] = cv;
            float r = rrow[p];
            hrow[p] = f2bf(r * tanhf_(cv) + (1.0f - r) * bf2f(xbrow[p]));
        }
        __syncthreads();
    }
}

// ---------------------------------------------------------------------------
extern "C" void kernel_launch(void* const* d_in, const int* in_sizes, int n_in,
                              void* d_out, int out_size, void* d_ws, size_t ws_size,
                              hipStream_t stream)
{
    const float* oper  = (const float*)d_in[0];
    const float* tbf   = (const float*)d_in[1];
    const float* ftf   = (const float*)d_in[2];
    const float* jnf   = (const float*)d_in[3];
    const float* c_a   = (const float*)d_in[4];
    const float* c_b   = (const float*)d_in[5];
    const float* w_op1 = (const float*)d_in[6],  *b_op1 = (const float*)d_in[7];
    const float* w_op2 = (const float*)d_in[8],  *b_op2 = (const float*)d_in[9];
    const float* w_tb1 = (const float*)d_in[10], *b_tb1 = (const float*)d_in[11];
    const float* w_tb2 = (const float*)d_in[12], *b_tb2 = (const float*)d_in[13];
    const float* w_ft1 = (const float*)d_in[14], *b_ft1 = (const float*)d_in[15];
    const float* w_ft2 = (const float*)d_in[16], *b_ft2 = (const float*)d_in[17];
    const float* w_jn1 = (const float*)d_in[18], *b_jn1 = (const float*)d_in[19];
    const float* w_jn2 = (const float*)d_in[20], *b_jn2 = (const float*)d_in[21];
    const float* w_xou = (const float*)d_in[22], *b_xou = (const float*)d_in[23];
    const float* w_ab  = (const float*)d_in[24], *b_ab  = (const float*)d_in[25];
    const float* w_btoa= (const float*)d_in[26], *b_btoa= (const float*)d_in[27];
    const float* w_ca  = (const float*)d_in[28], *b_ca  = (const float*)d_in[29];
    const float* w_cb  = (const float*)d_in[30], *b_cb  = (const float*)d_in[31];
    const float* w_o1  = (const float*)d_in[32], *b_o1  = (const float*)d_in[33];
    const float* w_o2  = (const float*)d_in[34], *b_o2  = (const float*)d_in[35];

    char* WS = (char*)d_ws;
    short* wT_xou  = (short*)WS;                 // 196608
    short* wT_btoa = wT_xou  + 196608;           // 81920
    short* wT_ca   = wT_btoa + 81920;            // 65536
    short* wT_cb   = wT_ca   + 65536;            // 65536
    short* wT_ab   = wT_cb   + 65536;            // 65536
    short* wT_o1   = wT_ab   + 65536;            // 32768
    short* W1T     = wT_o1   + 32768;            // 24576 (256 x 96)
    short* W2T     = W1T     + 24576;            // 65536 (256 x 256)
    float* b1cat   = (float*)(W2T + 65536);      // 256
    float* b2cat   = b1cat + 256;                // 256

    const size_t MB = 1 << 20;
    const size_t OFF_XF   = 2 * MB;                              // 6.3 MB node-major
    const size_t OFF_HE   = OFF_XF  + (size_t)32768 * 96 * 2;    // henc_T 16 MB
    const size_t OFF_X    = OFF_HE  + (size_t)256 * NT * 2;      // x_T 16 MB
    const size_t OFF_XX   = OFF_X   + (size_t)256 * NT * 2;      // xx_T 32 MB
    const size_t OFF_FF   = OFF_XX  + (size_t)256 * NT * 4;      // ff_T 32 MB
    const size_t OFF_RR   = OFF_FF  + (size_t)256 * NT * 4;      // rr_T 32 MB
    const size_t OFF_C    = OFF_RR  + (size_t)256 * NT * 4;      // c_T 64 MB
    const size_t OFF_H    = OFF_C   + (size_t)256 * CSTRIDE * 4; // h_T 16 MB
    const size_t OFF_CB   = OFF_H   + (size_t)256 * NT * 2;      // cb_T 16 MB
    const size_t OFF_WA   = OFF_CB  + (size_t)256 * NT * 2;      // wa_T/t_T 16 MB
    const size_t OFF_CAT  = OFF_WA  + (size_t)256 * NT * 2;      // caf_T 32 MB

    short* xfeat = (short*)(WS + OFF_XF);
    short* hencT = (short*)(WS + OFF_HE);
    short* xT    = (short*)(WS + OFF_X);
    float* xxT   = (float*)(WS + OFF_XX);
    float* ffT   = (float*)(WS + OFF_FF);
    float* rrT   = (float*)(WS + OFF_RR);
    float* cT    = (float*)(WS + OFF_C);
    short* hT    = (short*)(WS + OFF_H);
    short* cbT   = (short*)(WS + OFF_CB);
    short* waT   = (short*)(WS + OFF_WA);
    float* cafT  = (float*)(WS + OFF_CAT);
    float* out   = (float*)d_out;
    const float* calf = c_a + (size_t)I_NODES * 256;   // [32768 x 256] fp32
    const float* cbl  = c_b + (size_t)I_NODES * 320;   // [32768 x 320] fp32

    // 1. prep (weights + features + leaf-output constant), 3777024 items
    prep_all<<<14754, 256, 0, stream>>>(
        w_xou, w_btoa, w_ca, w_cb, w_ab, w_o1,
        w_op1, w_tb1, w_ft1, w_jn1, w_op2, w_tb2, w_ft2, w_jn2,
        b_op1, b_tb1, b_ft1, b_jn1, b_op2, b_tb2, b_ft2, b_jn2,
        oper, tbf, ftf, jnf, b_o1, w_o2, b_o2,
        wT_xou, wT_btoa, wT_ca, wT_cb, wT_ab, wT_o1, W1T, W2T, b1cat, b2cat,
        xfeat, out);
    transpose_caf<<<dim3(512, 4), 256, 0, stream>>>(calf, cafT);

    // 2. encoder: henc_T = relu(W1T @ xfeat) ; x_T = relu(W2T @ henc_T)
    gemm_t<1, 2, 0, 0><<<dim3(2, 256), 256, 0, stream>>>(
        W1T, xfeat, b1cat, nullptr, nullptr, nullptr, hencT,
        nullptr, nullptr, nullptr, nullptr, nullptr, nullptr, 96, 0, NT, 0);
    gemm_t<1, 2, 0, 1><<<dim3(2, 256), 256, 0, stream>>>(
        W2T, hencT, b2cat, nullptr, nullptr, nullptr, xT,
        nullptr, nullptr, nullptr, nullptr, nullptr, nullptr, 256, NT, NT, 0);

    // 3. xou: rows 0-255 xx (raw), 256-511 ff (sig), 512-767 rr (sig)
    gemm_t<0, 1, 0, 1><<<dim3(6, 256), 256, 0, stream>>>(
        wT_xou, xT, b_xou, xxT, ffT, rrT, nullptr,
        nullptr, nullptr, nullptr, nullptr, nullptr, nullptr, 256, NT, NT, 0);

    // 4. leaf chain: (cb_T | wa_T) -> t_T (fused wb+t) -> c_T leaf region
    gemm_leafpair<<<dim3(2, 256, 2), 256, 0, stream>>>(
        wT_btoa, cbl, b_btoa, cbT, wT_ca, calf, b_ca, waT);
    gemm_t<0, 3, 0, 1><<<dim3(2, 256), 256, 0, stream>>>(
        wT_cb, cbT, b_cb, nullptr, nullptr, nullptr, waT /* t in-place */,
        cafT, waT, cbT, nullptr, nullptr, nullptr, 256, NT, NT, 0);
    gemm_t<1, 0, 0, 1><<<dim3(2, 256), 256, 0, stream>>>(
        wT_ab, waT, b_ab, cT, nullptr, nullptr, nullptr,
        nullptr, nullptr, nullptr, nullptr, nullptr, nullptr,
        256, NT, CSTRIDE, I_NODES);

    // 5. all 15 levels, one block per channel, block-local sync only
    levels_T<<<256, 1024, 0, stream>>>(cT, ffT, xxT, rrT, xT, hT);

    // 6. output head fused with final dot+sigmoid (internal nodes)
    gemm_t<1, 4, 0, 1><<<dim3(1, 256), 256, 0, stream>>>(
        wT_o1, hT, b_o1, nullptr, nullptr, nullptr, nullptr,
        nullptr, nullptr, nullptr, w_o2, b_o2, out, 256, NT, NT, 0);
}